// Round 7
// baseline (162.808 us; speedup 1.0000x reference)
//
#include <hip/hip_runtime.h>
#include <cstdint>
#include <cstddef>

typedef short bf16x8 __attribute__((ext_vector_type(8)));
typedef float f32x4 __attribute__((ext_vector_type(4)));

#define EPS 1e-3f

__device__ __forceinline__ short f32_to_bf16s(float f) {
    union { float f; uint32_t u; } v; v.f = f;
    return (short)((v.u + 0x7FFFu + ((v.u >> 16) & 1u)) >> 16);
}

// K0: wt[kp][ci] = bf16(W[ci][kp]) (192x64); at[w][k] = bf16(A[p][v][w]) (32x96, k=p*25+v, zero-padded)
__global__ __launch_bounds__(256) void prep_kernel(const float* __restrict__ A,
                                                   const float* __restrict__ W,
                                                   unsigned short* __restrict__ wt,
                                                   unsigned short* __restrict__ at) {
    int idx = blockIdx.x * 256 + threadIdx.x;
    if (idx < 12288) {
        int kp = idx >> 6, ci = idx & 63;
        wt[idx] = (unsigned short)f32_to_bf16s(W[ci * 192 + kp]);
    } else {
        int j = idx - 12288;
        if (j < 3072) {
            int w = j / 96, k = j - w * 96;
            float val = 0.f;
            if (w < 25 && k < 75) {
                int p = k / 25, v = k - p * 25;
                val = A[(p * 25 + v) * 25 + w];
            }
            at[j] = (unsigned short)f32_to_bf16s(val);
        }
    }
}

// phase-1 halves: load 16 window values / fold into xwL. Paired at call site so two
// units' loads are in flight before either consume (2 latency exposures, not 4).
__device__ __forceinline__ void p1_load(const float* __restrict__ x, int n, int l0,
                                        int cidx, float* v16, int& ci, int& v) {
    ci = cidx / 25; v = cidx - ci * 25;
    const float* xp = x + (size_t)(n * 64 + ci) * 7500 + v;
    #pragma unroll
    for (int i = 0; i < 16; ++i) {
        int l = l0 - 8 + i;
        v16[i] = (l >= 0 && l < 300) ? xp[l * 25] : 0.f;
    }
}

__device__ __forceinline__ void p1_store(short* __restrict__ smem, int ci, int v,
                                         const float* v16) {
    float run = v16[0] + v16[1] + v16[2] + v16[3]
              + v16[4] + v16[5] + v16[6] + v16[7];
    short* wb = &smem[(ci >> 3) * 1656 + (ci & 7)];
    #pragma unroll
    for (int j = 0; j < 8; ++j) {
        run += v16[j + 8];
        wb[(j * 25 + v) * 8] = f32_to_bf16s(run);
        run -= v16[j];
    }
}

// Mega v8 = v7 (71us: 1 sample/block, 4 blocks/CU = 32 waves/CU, XCD swizzle) +
//  (a) Ys stride 104->105: kills the 8-way bank conflict on GEMM2's ds_read_b128
//      (52*lcol mod 32 hit 8 start-banks x8 lanes; 105 gives 16 distinct, ~2-way=free)
//  (b) phase-1 reps paired (2x32-load batches instead of 4x16): 2 latency exposures.
//      b2 load moved after barrier 1 to free 24 VGPRs during phase-1 (cap is 64!).
__global__ __launch_bounds__(512, 4) void mega_kernel(
    const float* __restrict__ x,
    const unsigned short* __restrict__ wt,
    const unsigned short* __restrict__ at,
    const float* __restrict__ gamma, const float* __restrict__ beta,
    const float* __restrict__ mean, const float* __restrict__ var,
    float* __restrict__ out) {
    // XCD-chunked swizzle (v7-verified: FETCH 92->44 MB): bijective, 1216 = 8*152.
    const int lin = blockIdx.x + 38 * blockIdx.y;        // 0..1215
    const int logical = (lin & 7) * 152 + (lin >> 3);
    const int ch = logical % 38;
    const int n  = logical / 38;

    const int l0 = ch * 8;
    const int tid = threadIdx.x;
    const int wv = tid >> 6, lane = tid & 63, q = lane >> 4, lcol = lane & 15;

    __shared__ __align__(16) short smem[13440];   // xwL (13248) then Ys 128x105 (13440)
    __shared__ float scs[64], shs[64];

    if (tid < 64) {
        float sc = gamma[tid] * rsqrtf(var[tid] + EPS);
        scs[tid] = sc;
        shs[tid] = beta[tid] - mean[tid] * sc;
    }

    // Phase 1: paired reps — units (tid, tid+512) then (tid+1024, tid+1536).
    // rep0: both branches fully active; rep1: A active, B only wave 0 (uniform skip).
    #pragma unroll 1
    for (int rep = 0; rep < 2; ++rep) {
        int cA = tid + rep * 1024;
        int cB = cA + 512;
        bool actA = cA < 1600, actB = cB < 1600;
        float va[16], vb[16];
        int ciA, vA, ciB, vB;
        if (actA) p1_load(x, n, l0, cA, va, ciA, vA);
        if (actB) p1_load(x, n, l0, cB, vb, ciB, vB);
        if (actA) p1_store(smem, ciA, vA, va);
        if (actB) p1_store(smem, ciB, vB, vb);
    }
    __syncthreads();   // barrier 1: xwL ready

    // b2 fragments (at, L2-resident) — loaded HERE so phase-1 has VGPR headroom;
    // latency hides under b1 loads + zero-init + group-0 MFMA1.
    bf16x8 b2[2][3];
    #pragma unroll
    for (int nt = 0; nt < 2; ++nt)
        #pragma unroll
        for (int s = 0; s < 3; ++s)
            b2[nt][s] = *(const bf16x8*)(at + (size_t)(nt * 16 + lcol) * 96 + 32 * s + 8 * q);

    // b1 fragments: B[k=ci][col], cols wv*25 + nt*16 + lcol (<=206; cols>=200 are
    // stale-but-finite garbage whose D-columns map to w>=25 and are never stored)
    bf16x8 b1[2][2];
    #pragma unroll
    for (int nt = 0; nt < 2; ++nt) {
        int col = wv * 25 + nt * 16 + lcol;
        #pragma unroll
        for (int s = 0; s < 2; ++s)
            b1[nt][s] = *(const bf16x8*)&smem[(4 * s + q) * 1656 + col * 8];
    }
    __syncthreads();   // barrier 2: all xwL reads done; smem becomes Ys (stride 105)

    // Zero own Ys slab cols [64,96): [64,75) is stage-overwritten each group,
    // [75,96) is the pad GEMM2 reads (reads span cols [0,96)).
    #pragma unroll
    for (int i = lane; i < 512; i += 64) {
        int r = i >> 5, cc = 64 + (i & 31);
        smem[(wv * 16 + r) * 105 + cc] = 0;
    }

    const int lg = l0 + wv;
    const size_t outrow = ((size_t)n * 64 * 300 + lg) * 25;   // + c*7500 + w

    #pragma unroll 1
    for (int g = 0; g < 4; ++g) {
        // a1 fragments for this c-group (wt, L1/L2-resident)
        bf16x8 a1[3][2];
        #pragma unroll
        for (int mt = 0; mt < 3; ++mt)
            #pragma unroll
            for (int s = 0; s < 2; ++s)
                a1[mt][s] = *(const bf16x8*)(wt + (size_t)(g * 48 + mt * 16 + lcol) * 64 + 32 * s + 8 * q);

        // GEMM1: M=48 (kp of group g), N=32 (own l, v+pad), K=64
        f32x4 acc[3][2];
        #pragma unroll
        for (int mt = 0; mt < 3; ++mt)
            #pragma unroll
            for (int nt = 0; nt < 2; ++nt) acc[mt][nt] = (f32x4){0.f, 0.f, 0.f, 0.f};
        #pragma unroll
        for (int s = 0; s < 2; ++s)
            #pragma unroll
            for (int mt = 0; mt < 3; ++mt) {
                bf16x8 av = a1[mt][s];
                #pragma unroll
                for (int nt = 0; nt < 2; ++nt)
                    acc[mt][nt] = __builtin_amdgcn_mfma_f32_16x16x32_bf16(av, b1[nt][s], acc[mt][nt], 0, 0, 0);
            }

        // Residual prefetch (L2-hot: same rows fetched by phase 1 of this block)
        float res[2][4];
        #pragma unroll
        for (int nt = 0; nt < 2; ++nt) {
            int w = nt * 16 + lcol;
            bool val = (w < 25) && (lg < 300);
            #pragma unroll
            for (int r = 0; r < 4; ++r) {
                int c = g * 16 + 4 * q + r;
                res[nt][r] = val ? x[outrow + (size_t)c * 7500 + w] : 0.f;
            }
        }

        // Stage D -> own Ys slab rows (wv*16+cl), col 25p+v   (wave-private, no barrier)
        #pragma unroll
        for (int mt = 0; mt < 3; ++mt)
            #pragma unroll
            for (int nt = 0; nt < 2; ++nt) {
                int v = nt * 16 + lcol;
                if (v < 25) {
                    #pragma unroll
                    for (int r = 0; r < 4; ++r) {
                        int kpl = mt * 16 + 4 * q + r;
                        int cl = kpl / 3, p = kpl - 3 * cl;
                        smem[(wv * 16 + cl) * 105 + 25 * p + v] = f32_to_bf16s(acc[mt][nt][r]);
                    }
                }
            }

        // GEMM2: M=16 (cl), N=32 (w), K=96 — reads own slab (compiler orders via lgkmcnt)
        f32x4 c0 = {0.f, 0.f, 0.f, 0.f}, c1 = {0.f, 0.f, 0.f, 0.f};
        #pragma unroll
        for (int s = 0; s < 3; ++s) {
            bf16x8 a2 = *(const bf16x8*)&smem[(wv * 16 + lcol) * 105 + 32 * s + 8 * q];
            c0 = __builtin_amdgcn_mfma_f32_16x16x32_bf16(a2, b2[0][s], c0, 0, 0, 0);
            c1 = __builtin_amdgcn_mfma_f32_16x16x32_bf16(a2, b2[1][s], c1, 0, 0, 0);
        }

        // Epilogue: BN + ReLU + residual + ReLU
        if (lg < 300) {
            #pragma unroll
            for (int nt = 0; nt < 2; ++nt) {
                int w = nt * 16 + lcol;
                if (w < 25) {
                    f32x4 cc = nt ? c1 : c0;
                    #pragma unroll
                    for (int r = 0; r < 4; ++r) {
                        int c = g * 16 + 4 * q + r;
                        float o = fmaxf(cc[r] * scs[c] + shs[c], 0.f);
                        out[outrow + (size_t)c * 7500 + w] = fmaxf(o + res[nt][r], 0.f);
                    }
                }
            }
        }
    }
}

extern "C" void kernel_launch(void* const* d_in, const int* in_sizes, int n_in,
                              void* d_out, int out_size, void* d_ws, size_t ws_size,
                              hipStream_t stream) {
    const float* x     = (const float*)d_in[0];
    const float* A     = (const float*)d_in[1];
    const float* W     = (const float*)d_in[2];
    const float* gamma = (const float*)d_in[3];
    const float* beta  = (const float*)d_in[4];
    const float* mean  = (const float*)d_in[5];
    const float* var   = (const float*)d_in[6];
    float* out = (float*)d_out;

    char* ws = (char*)d_ws;
    unsigned short* wt = (unsigned short*)ws;               // 24,576 B
    unsigned short* at = (unsigned short*)(ws + 24576);     // 6,144 B

    prep_kernel<<<60, 256, 0, stream>>>(A, W, wt, at);
    mega_kernel<<<dim3(38, 32), 512, 0, stream>>>(x, wt, at, gamma, beta, mean, var, out);
}